// Round 1
// baseline (880.624 us; speedup 1.0000x reference)
//
#include <hip/hip_runtime.h>
#include <math.h>

// ---------------- CSR build ----------------

__global__ void detect64_kernel(const int* __restrict__ ei, int E, int* __restrict__ flag) {
    // If edge_index is int64, every odd int32 word (high word) is 0 (values < 2^31).
    __shared__ int any;
    if (threadIdx.x == 0) any = 0;
    __syncthreads();
    int lim = 1024;
    for (int i = threadIdx.x; i < lim; i += 256) {
        if (ei[2 * i + 1] != 0) { any = 1; break; }
    }
    __syncthreads();
    if (threadIdx.x == 0) *flag = (any ? 0 : 1);  // 1 => int64
}

__device__ __forceinline__ int edge_src(const int* ei, int E, int i, int is64) {
    return is64 ? ei[2 * i] : ei[i];
}
__device__ __forceinline__ int edge_dst(const int* ei, int E, int i, int is64) {
    return is64 ? ei[2 * (E + i)] : ei[E + i];
}

__global__ void count_deg_kernel(const int* __restrict__ ei, int E, int N,
                                 const int* __restrict__ flag, int* __restrict__ deg) {
    int i = blockIdx.x * blockDim.x + threadIdx.x;
    int total = E + N;
    if (i >= total) return;
    int is64 = *flag;
    int d = (i < E) ? edge_dst(ei, E, i, is64) : (i - E);
    atomicAdd(&deg[d], 1);
}

__global__ void scan_partial_kernel(const int* __restrict__ deg, int M, int* __restrict__ partials) {
    __shared__ int s[256];
    int t = threadIdx.x;
    int i = blockIdx.x * 256 + t;
    int v = (i < M) ? deg[i] : 0;
    s[t] = v;
    __syncthreads();
    for (int off = 128; off > 0; off >>= 1) {
        if (t < off) s[t] += s[t + off];
        __syncthreads();
    }
    if (t == 0) partials[blockIdx.x] = s[0];
}

__global__ void scan_partials_kernel(int* __restrict__ partials, int nb) {
    __shared__ int s[512];
    int t = threadIdx.x;
    int v = (t < nb) ? partials[t] : 0;
    s[t] = v;
    __syncthreads();
    for (int off = 1; off < 512; off <<= 1) {
        int x = (t >= off) ? s[t - off] : 0;
        __syncthreads();
        s[t] += x;
        __syncthreads();
    }
    if (t < nb) partials[t] = s[t] - v;  // exclusive
}

__global__ void scan_apply_kernel(const int* __restrict__ deg, int M,
                                  const int* __restrict__ partials, int* __restrict__ rowptr) {
    __shared__ int s[256];
    int t = threadIdx.x;
    int i = blockIdx.x * 256 + t;
    int v = (i < M) ? deg[i] : 0;
    s[t] = v;
    __syncthreads();
    for (int off = 1; off < 256; off <<= 1) {
        int x = (t >= off) ? s[t - off] : 0;
        __syncthreads();
        s[t] += x;
        __syncthreads();
    }
    if (i < M) rowptr[i] = s[t] - v + partials[blockIdx.x];
}

__global__ void fill_col_kernel(const int* __restrict__ ei, int E, int N,
                                const int* __restrict__ flag,
                                int* __restrict__ cursor, int* __restrict__ col) {
    int i = blockIdx.x * blockDim.x + threadIdx.x;
    int total = E + N;
    if (i >= total) return;
    int is64 = *flag;
    int s, d;
    if (i < E) { s = edge_src(ei, E, i, is64); d = edge_dst(ei, E, i, is64); }
    else       { s = i - E; d = i - E; }
    int pos = atomicAdd(&cursor[d], 1);
    col[pos] = s;
}

// ---------------- GEMM 1: h1 = x @ W1, fused e_src/e_dst (8 heads x 8 dim) ----------------

#define KT1 50
__global__ __launch_bounds__(256) void gemm1_kernel(
    const float* __restrict__ x, const float* __restrict__ W,
    const float* __restrict__ asrc, const float* __restrict__ adst,
    float* __restrict__ h, float* __restrict__ es, float* __restrict__ ed, int N) {
    __shared__ __align__(16) float Ws[KT1 * 64];
    __shared__ float xs[128 * (KT1 + 1)];
    const int tx = threadIdx.x;
    const int cg = tx & 7;        // col group: cols cg*8 .. cg*8+7  (== head for layer 1)
    const int rg = tx >> 3;       // 0..31, rows rg*4 .. rg*4+3
    const int rowBase = blockIdx.x * 128;
    float acc[4][8];
#pragma unroll
    for (int r = 0; r < 4; r++)
#pragma unroll
        for (int c = 0; c < 8; c++) acc[r][c] = 0.f;

    for (int kt = 0; kt < 300; kt += KT1) {
        for (int i = tx; i < KT1 * 64; i += 256) Ws[i] = W[kt * 64 + i];
        for (int i = tx; i < 128 * KT1; i += 256) {
            int rr = i / KT1, cc = i - rr * KT1;
            int row = rowBase + rr;
            xs[rr * (KT1 + 1) + cc] = (row < N) ? x[(size_t)row * 300 + kt + cc] : 0.f;
        }
        __syncthreads();
        for (int k = 0; k < KT1; k++) {
            float4 w0 = *(const float4*)&Ws[k * 64 + cg * 8];
            float4 w1 = *(const float4*)&Ws[k * 64 + cg * 8 + 4];
#pragma unroll
            for (int r = 0; r < 4; r++) {
                float xv = xs[(rg * 4 + r) * (KT1 + 1) + k];
                acc[r][0] = fmaf(xv, w0.x, acc[r][0]);
                acc[r][1] = fmaf(xv, w0.y, acc[r][1]);
                acc[r][2] = fmaf(xv, w0.z, acc[r][2]);
                acc[r][3] = fmaf(xv, w0.w, acc[r][3]);
                acc[r][4] = fmaf(xv, w1.x, acc[r][4]);
                acc[r][5] = fmaf(xv, w1.y, acc[r][5]);
                acc[r][6] = fmaf(xv, w1.z, acc[r][6]);
                acc[r][7] = fmaf(xv, w1.w, acc[r][7]);
            }
        }
        __syncthreads();
    }
#pragma unroll
    for (int r = 0; r < 4; r++) {
        int row = rowBase + rg * 4 + r;
        if (row >= N) continue;
        float4 o0 = make_float4(acc[r][0], acc[r][1], acc[r][2], acc[r][3]);
        float4 o1 = make_float4(acc[r][4], acc[r][5], acc[r][6], acc[r][7]);
        *(float4*)&h[(size_t)row * 64 + cg * 8] = o0;
        *(float4*)&h[(size_t)row * 64 + cg * 8 + 4] = o1;
        float ps = 0.f, pd = 0.f;
#pragma unroll
        for (int c = 0; c < 8; c++) {
            ps = fmaf(acc[r][c], asrc[cg * 8 + c], ps);
            pd = fmaf(acc[r][c], adst[cg * 8 + c], pd);
        }
        es[row * 8 + cg] = ps;   // head == cg
        ed[row * 8 + cg] = pd;
    }
}

// ---------------- GEMM 2: h2 = h1post @ W2, fused scalar e_src/e_dst ----------------

__global__ __launch_bounds__(256) void gemm2_kernel(
    const float* __restrict__ xin, const float* __restrict__ W,
    const float* __restrict__ asrc, const float* __restrict__ adst,
    float* __restrict__ h, float* __restrict__ es, float* __restrict__ ed, int N) {
    __shared__ __align__(16) float Ws[64 * 64];
    __shared__ float xs[128 * 65];
    const int tx = threadIdx.x;
    const int cg = tx & 7;
    const int rg = tx >> 3;
    const int rowBase = blockIdx.x * 128;
    float acc[4][8];
#pragma unroll
    for (int r = 0; r < 4; r++)
#pragma unroll
        for (int c = 0; c < 8; c++) acc[r][c] = 0.f;

    for (int i = tx; i < 64 * 64; i += 256) Ws[i] = W[i];
    for (int i = tx; i < 128 * 64; i += 256) {
        int rr = i >> 6, cc = i & 63;
        int row = rowBase + rr;
        xs[rr * 65 + cc] = (row < N) ? xin[(size_t)row * 64 + cc] : 0.f;
    }
    __syncthreads();
    for (int k = 0; k < 64; k++) {
        float4 w0 = *(const float4*)&Ws[k * 64 + cg * 8];
        float4 w1 = *(const float4*)&Ws[k * 64 + cg * 8 + 4];
#pragma unroll
        for (int r = 0; r < 4; r++) {
            float xv = xs[(rg * 4 + r) * 65 + k];
            acc[r][0] = fmaf(xv, w0.x, acc[r][0]);
            acc[r][1] = fmaf(xv, w0.y, acc[r][1]);
            acc[r][2] = fmaf(xv, w0.z, acc[r][2]);
            acc[r][3] = fmaf(xv, w0.w, acc[r][3]);
            acc[r][4] = fmaf(xv, w1.x, acc[r][4]);
            acc[r][5] = fmaf(xv, w1.y, acc[r][5]);
            acc[r][6] = fmaf(xv, w1.z, acc[r][6]);
            acc[r][7] = fmaf(xv, w1.w, acc[r][7]);
        }
    }
#pragma unroll
    for (int r = 0; r < 4; r++) {
        int row = rowBase + rg * 4 + r;
        float ps = 0.f, pd = 0.f;
        if (row < N) {
            float4 o0 = make_float4(acc[r][0], acc[r][1], acc[r][2], acc[r][3]);
            float4 o1 = make_float4(acc[r][4], acc[r][5], acc[r][6], acc[r][7]);
            *(float4*)&h[(size_t)row * 64 + cg * 8] = o0;
            *(float4*)&h[(size_t)row * 64 + cg * 8 + 4] = o1;
#pragma unroll
            for (int c = 0; c < 8; c++) {
                ps = fmaf(acc[r][c], asrc[cg * 8 + c], ps);
                pd = fmaf(acc[r][c], adst[cg * 8 + c], pd);
            }
        }
        // reduce over the 8 col-groups (lanes differing in bits 0..2)
        for (int off = 1; off < 8; off <<= 1) {
            ps += __shfl_xor(ps, off);
            pd += __shfl_xor(pd, off);
        }
        if (cg == 0 && row < N) { es[row] = ps; ed[row] = pd; }
    }
}

// ---------------- Aggregation layer 1: online edge-softmax, 8 heads, fused bias+ELU ----------------

__global__ __launch_bounds__(256) void agg1_kernel(
    const int* __restrict__ rowptr, const int* __restrict__ col,
    const float* __restrict__ h, const float* __restrict__ es, const float* __restrict__ ed,
    const float* __restrict__ b, float* __restrict__ out, int N) {
    int node = blockIdx.x * 4 + (threadIdx.x >> 6);
    int lane = threadIdx.x & 63;
    if (node >= N) return;
    int hh = lane >> 3;
    float edv = ed[node * 8 + hh];
    float m = -1e30f, l = 0.f, acc = 0.f;
    int beg = rowptr[node], end = rowptr[node + 1];
    for (int i = beg; i < end; i++) {
        int s = col[i];
        float e = es[s * 8 + hh] + edv;
        e = (e > 0.f) ? e : 0.2f * e;
        float hv = h[(size_t)s * 64 + lane];
        float mn = fmaxf(m, e);
        float wexp = __expf(e - mn);
        float sc = __expf(m - mn);
        acc = acc * sc + wexp * hv;
        l = l * sc + wexp;
        m = mn;
    }
    float o = acc / l + b[lane];
    o = (o > 0.f) ? o : expm1f(o);
    out[(size_t)node * 64 + lane] = o;
}

// ---------------- Aggregation layer 2: 1 head, fused bias + log_softmax ----------------

__global__ __launch_bounds__(256) void agg2_kernel(
    const int* __restrict__ rowptr, const int* __restrict__ col,
    const float* __restrict__ h, const float* __restrict__ es, const float* __restrict__ ed,
    const float* __restrict__ b, float* __restrict__ out, int N) {
    int node = blockIdx.x * 4 + (threadIdx.x >> 6);
    int lane = threadIdx.x & 63;
    if (node >= N) return;
    float edv = ed[node];
    float m = -1e30f, l = 0.f, acc = 0.f;
    int beg = rowptr[node], end = rowptr[node + 1];
    for (int i = beg; i < end; i++) {
        int s = col[i];
        float e = es[s] + edv;
        e = (e > 0.f) ? e : 0.2f * e;
        float hv = h[(size_t)s * 64 + lane];
        float mn = fmaxf(m, e);
        float wexp = __expf(e - mn);
        float sc = __expf(m - mn);
        acc = acc * sc + wexp * hv;
        l = l * sc + wexp;
        m = mn;
    }
    float o = acc / l + b[lane];
    // log_softmax over 64 lanes
    float M = o;
    for (int off = 32; off > 0; off >>= 1) M = fmaxf(M, __shfl_xor(M, off));
    float se = __expf(o - M);
    for (int off = 32; off > 0; off >>= 1) se += __shfl_xor(se, off);
    out[(size_t)node * 64 + lane] = o - M - logf(se);
}

// ---------------- launch ----------------

extern "C" void kernel_launch(void* const* d_in, const int* in_sizes, int n_in,
                              void* d_out, int out_size, void* d_ws, size_t ws_size,
                              hipStream_t stream) {
    const float* x   = (const float*)d_in[0];
    const int*   ei  = (const int*)d_in[1];
    const float* W1  = (const float*)d_in[2];
    const float* as1 = (const float*)d_in[3];
    const float* ad1 = (const float*)d_in[4];
    const float* b1  = (const float*)d_in[5];
    const float* W2  = (const float*)d_in[6];
    const float* as2 = (const float*)d_in[7];
    const float* ad2 = (const float*)d_in[8];
    const float* b2  = (const float*)d_in[9];
    const int N = in_sizes[0] / 300;
    const int E = in_sizes[1] / 2;
    (void)n_in; (void)out_size; (void)ws_size;

    char* w = (char*)d_ws;
    auto alloc = [&](size_t bytes) -> char* {
        char* p = w;
        w += (bytes + 255) & ~(size_t)255;
        return p;
    };
    int*   flag     = (int*)alloc(256);
    int*   deg      = (int*)alloc((size_t)(N + 1) * 4);
    int*   rowptr   = (int*)alloc((size_t)(N + 1) * 4);
    int*   cursor   = (int*)alloc((size_t)(N + 1) * 4);
    int*   partials = (int*)alloc(1024 * 4);
    int*   col      = (int*)alloc((size_t)(E + N) * 4);
    float* h1       = (float*)alloc((size_t)N * 64 * 4);
    float* h1p      = (float*)alloc((size_t)N * 64 * 4);
    float* es1      = (float*)alloc((size_t)N * 8 * 4);
    float* ed1      = (float*)alloc((size_t)N * 8 * 4);
    float* es2      = (float*)alloc((size_t)N * 4);
    float* ed2      = (float*)alloc((size_t)N * 4);
    float* h2 = h1;  // h1 dead after agg1

    hipMemsetAsync(deg, 0, (size_t)(N + 1) * sizeof(int), stream);
    detect64_kernel<<<1, 256, 0, stream>>>(ei, E, flag);

    int total = E + N;
    count_deg_kernel<<<(total + 255) / 256, 256, 0, stream>>>(ei, E, N, flag, deg);
    int M = N + 1, nb = (M + 255) / 256;  // nb must be <= 512
    scan_partial_kernel<<<nb, 256, 0, stream>>>(deg, M, partials);
    scan_partials_kernel<<<1, 512, 0, stream>>>(partials, nb);
    scan_apply_kernel<<<nb, 256, 0, stream>>>(deg, M, partials, rowptr);
    hipMemcpyAsync(cursor, rowptr, (size_t)M * 4, hipMemcpyDeviceToDevice, stream);
    fill_col_kernel<<<(total + 255) / 256, 256, 0, stream>>>(ei, E, N, flag, cursor, col);

    gemm1_kernel<<<(N + 127) / 128, 256, 0, stream>>>(x, W1, as1, ad1, h1, es1, ed1, N);
    agg1_kernel<<<(N + 3) / 4, 256, 0, stream>>>(rowptr, col, h1, es1, ed1, b1, h1p, N);
    gemm2_kernel<<<(N + 127) / 128, 256, 0, stream>>>(h1p, W2, as2, ad2, h2, es2, ed2, N);
    agg2_kernel<<<(N + 3) / 4, 256, 0, stream>>>(rowptr, col, h2, es2, ed2, b2, (float*)d_out, N);
}

// Round 2
// 712.946 us; speedup vs baseline: 1.2352x; 1.2352x over previous
//
#include <hip/hip_runtime.h>
#include <math.h>

// ---------------- CSR build ----------------

__global__ void detect64_kernel(const int* __restrict__ ei, int E, int* __restrict__ flag) {
    // If edge_index is int64, every odd int32 word (high word) is 0 (values < 2^31).
    __shared__ int any;
    if (threadIdx.x == 0) any = 0;
    __syncthreads();
    int lim = 1024;
    for (int i = threadIdx.x; i < lim; i += 256) {
        if (ei[2 * i + 1] != 0) { any = 1; break; }
    }
    __syncthreads();
    if (threadIdx.x == 0) *flag = (any ? 0 : 1);  // 1 => int64
}

__device__ __forceinline__ int edge_src(const int* ei, int E, int i, int is64) {
    return is64 ? ei[2 * i] : ei[i];
}
__device__ __forceinline__ int edge_dst(const int* ei, int E, int i, int is64) {
    return is64 ? ei[2 * (E + i)] : ei[E + i];
}

__global__ void count_deg_kernel(const int* __restrict__ ei, int E, int N,
                                 const int* __restrict__ flag, int* __restrict__ deg) {
    int i = blockIdx.x * blockDim.x + threadIdx.x;
    int total = E + N;
    if (i >= total) return;
    int is64 = *flag;
    int d = (i < E) ? edge_dst(ei, E, i, is64) : (i - E);
    atomicAdd(&deg[d], 1);
}

__global__ void scan_partial_kernel(const int* __restrict__ deg, int M, int* __restrict__ partials) {
    __shared__ int s[256];
    int t = threadIdx.x;
    int i = blockIdx.x * 256 + t;
    int v = (i < M) ? deg[i] : 0;
    s[t] = v;
    __syncthreads();
    for (int off = 128; off > 0; off >>= 1) {
        if (t < off) s[t] += s[t + off];
        __syncthreads();
    }
    if (t == 0) partials[blockIdx.x] = s[0];
}

__global__ void scan_partials_kernel(int* __restrict__ partials, int nb) {
    __shared__ int s[512];
    int t = threadIdx.x;
    int v = (t < nb) ? partials[t] : 0;
    s[t] = v;
    __syncthreads();
    for (int off = 1; off < 512; off <<= 1) {
        int x = (t >= off) ? s[t - off] : 0;
        __syncthreads();
        s[t] += x;
        __syncthreads();
    }
    if (t < nb) partials[t] = s[t] - v;  // exclusive
}

__global__ void scan_apply_kernel(const int* __restrict__ deg, int M,
                                  const int* __restrict__ partials, int* __restrict__ rowptr) {
    __shared__ int s[256];
    int t = threadIdx.x;
    int i = blockIdx.x * 256 + t;
    int v = (i < M) ? deg[i] : 0;
    s[t] = v;
    __syncthreads();
    for (int off = 1; off < 256; off <<= 1) {
        int x = (t >= off) ? s[t - off] : 0;
        __syncthreads();
        s[t] += x;
        __syncthreads();
    }
    if (i < M) rowptr[i] = s[t] - v + partials[blockIdx.x];
}

__global__ void fill_col_kernel(const int* __restrict__ ei, int E, int N,
                                const int* __restrict__ flag,
                                int* __restrict__ cursor, int* __restrict__ col) {
    int i = blockIdx.x * blockDim.x + threadIdx.x;
    int total = E + N;
    if (i >= total) return;
    int is64 = *flag;
    int s, d;
    if (i < E) { s = edge_src(ei, E, i, is64); d = edge_dst(ei, E, i, is64); }
    else       { s = i - E; d = i - E; }
    int pos = atomicAdd(&cursor[d], 1);
    col[pos] = s;
}

// ---------------- GEMM 1: h1 = x @ W1, fused e_src/e_dst (8 heads x 8 dim) ----------------

#define KT1 50
__global__ __launch_bounds__(256) void gemm1_kernel(
    const float* __restrict__ x, const float* __restrict__ W,
    const float* __restrict__ asrc, const float* __restrict__ adst,
    float* __restrict__ h, float* __restrict__ es, float* __restrict__ ed, int N) {
    __shared__ __align__(16) float Ws[KT1 * 64];
    __shared__ float xs[128 * (KT1 + 1)];
    const int tx = threadIdx.x;
    const int cg = tx & 7;        // col group: cols cg*8 .. cg*8+7  (== head for layer 1)
    const int rg = tx >> 3;       // 0..31, rows rg*4 .. rg*4+3
    const int rowBase = blockIdx.x * 128;
    float acc[4][8];
#pragma unroll
    for (int r = 0; r < 4; r++)
#pragma unroll
        for (int c = 0; c < 8; c++) acc[r][c] = 0.f;

    for (int kt = 0; kt < 300; kt += KT1) {
        for (int i = tx; i < KT1 * 64; i += 256) Ws[i] = W[kt * 64 + i];
        for (int i = tx; i < 128 * KT1; i += 256) {
            int rr = i / KT1, cc = i - rr * KT1;
            int row = rowBase + rr;
            xs[rr * (KT1 + 1) + cc] = (row < N) ? x[(size_t)row * 300 + kt + cc] : 0.f;
        }
        __syncthreads();
        for (int k = 0; k < KT1; k++) {
            float4 w0 = *(const float4*)&Ws[k * 64 + cg * 8];
            float4 w1 = *(const float4*)&Ws[k * 64 + cg * 8 + 4];
#pragma unroll
            for (int r = 0; r < 4; r++) {
                float xv = xs[(rg * 4 + r) * (KT1 + 1) + k];
                acc[r][0] = fmaf(xv, w0.x, acc[r][0]);
                acc[r][1] = fmaf(xv, w0.y, acc[r][1]);
                acc[r][2] = fmaf(xv, w0.z, acc[r][2]);
                acc[r][3] = fmaf(xv, w0.w, acc[r][3]);
                acc[r][4] = fmaf(xv, w1.x, acc[r][4]);
                acc[r][5] = fmaf(xv, w1.y, acc[r][5]);
                acc[r][6] = fmaf(xv, w1.z, acc[r][6]);
                acc[r][7] = fmaf(xv, w1.w, acc[r][7]);
            }
        }
        __syncthreads();
    }
#pragma unroll
    for (int r = 0; r < 4; r++) {
        int row = rowBase + rg * 4 + r;
        if (row >= N) continue;
        float4 o0 = make_float4(acc[r][0], acc[r][1], acc[r][2], acc[r][3]);
        float4 o1 = make_float4(acc[r][4], acc[r][5], acc[r][6], acc[r][7]);
        *(float4*)&h[(size_t)row * 64 + cg * 8] = o0;
        *(float4*)&h[(size_t)row * 64 + cg * 8 + 4] = o1;
        float ps = 0.f, pd = 0.f;
#pragma unroll
        for (int c = 0; c < 8; c++) {
            ps = fmaf(acc[r][c], asrc[cg * 8 + c], ps);
            pd = fmaf(acc[r][c], adst[cg * 8 + c], pd);
        }
        es[row * 8 + cg] = ps;   // head == cg
        ed[row * 8 + cg] = pd;
    }
}

// ---------------- GEMM 2: h2 = h1post @ W2, fused scalar e_src/e_dst ----------------

__global__ __launch_bounds__(256) void gemm2_kernel(
    const float* __restrict__ xin, const float* __restrict__ W,
    const float* __restrict__ asrc, const float* __restrict__ adst,
    float* __restrict__ h, float* __restrict__ es, float* __restrict__ ed, int N) {
    __shared__ __align__(16) float Ws[64 * 64];
    __shared__ float xs[128 * 65];
    const int tx = threadIdx.x;
    const int cg = tx & 7;
    const int rg = tx >> 3;
    const int rowBase = blockIdx.x * 128;
    float acc[4][8];
#pragma unroll
    for (int r = 0; r < 4; r++)
#pragma unroll
        for (int c = 0; c < 8; c++) acc[r][c] = 0.f;

    for (int i = tx; i < 64 * 64; i += 256) Ws[i] = W[i];
    for (int i = tx; i < 128 * 64; i += 256) {
        int rr = i >> 6, cc = i & 63;
        int row = rowBase + rr;
        xs[rr * 65 + cc] = (row < N) ? xin[(size_t)row * 64 + cc] : 0.f;
    }
    __syncthreads();
    for (int k = 0; k < 64; k++) {
        float4 w0 = *(const float4*)&Ws[k * 64 + cg * 8];
        float4 w1 = *(const float4*)&Ws[k * 64 + cg * 8 + 4];
#pragma unroll
        for (int r = 0; r < 4; r++) {
            float xv = xs[(rg * 4 + r) * 65 + k];
            acc[r][0] = fmaf(xv, w0.x, acc[r][0]);
            acc[r][1] = fmaf(xv, w0.y, acc[r][1]);
            acc[r][2] = fmaf(xv, w0.z, acc[r][2]);
            acc[r][3] = fmaf(xv, w0.w, acc[r][3]);
            acc[r][4] = fmaf(xv, w1.x, acc[r][4]);
            acc[r][5] = fmaf(xv, w1.y, acc[r][5]);
            acc[r][6] = fmaf(xv, w1.z, acc[r][6]);
            acc[r][7] = fmaf(xv, w1.w, acc[r][7]);
        }
    }
#pragma unroll
    for (int r = 0; r < 4; r++) {
        int row = rowBase + rg * 4 + r;
        float ps = 0.f, pd = 0.f;
        if (row < N) {
            float4 o0 = make_float4(acc[r][0], acc[r][1], acc[r][2], acc[r][3]);
            float4 o1 = make_float4(acc[r][4], acc[r][5], acc[r][6], acc[r][7]);
            *(float4*)&h[(size_t)row * 64 + cg * 8] = o0;
            *(float4*)&h[(size_t)row * 64 + cg * 8 + 4] = o1;
#pragma unroll
            for (int c = 0; c < 8; c++) {
                ps = fmaf(acc[r][c], asrc[cg * 8 + c], ps);
                pd = fmaf(acc[r][c], adst[cg * 8 + c], pd);
            }
        }
        // reduce over the 8 col-groups (lanes differing in bits 0..2)
        for (int off = 1; off < 8; off <<= 1) {
            ps += __shfl_xor(ps, off);
            pd += __shfl_xor(pd, off);
        }
        if (cg == 0 && row < N) { es[row] = ps; ed[row] = pd; }
    }
}

// ---------------- Aggregation layer 1: online edge-softmax, 8 heads, fused bias+ELU ----------------
// 8-wide edge batching: 8 col loads, then 8 es + 8 h gathers all in flight,
// one online-softmax rescale per group of 8 (latency-bound fix, R1).

#define EB 8
__global__ __launch_bounds__(256) void agg1_kernel(
    const int* __restrict__ rowptr, const int* __restrict__ col,
    const float* __restrict__ h, const float* __restrict__ es, const float* __restrict__ ed,
    const float* __restrict__ b, float* __restrict__ out, int N) {
    int node = blockIdx.x * 4 + (threadIdx.x >> 6);
    int lane = threadIdx.x & 63;
    if (node >= N) return;
    int hh = lane >> 3;
    float edv = ed[node * 8 + hh];
    float m = -1e30f, l = 0.f, acc = 0.f;
    int beg = rowptr[node], end = rowptr[node + 1];
    for (int i = beg; i < end; i += EB) {
        int ss[EB];
#pragma unroll
        for (int j = 0; j < EB; j++) {
            int idx = i + j;
            ss[j] = col[idx < end ? idx : end - 1];
        }
        float ev[EB], hv[EB];
#pragma unroll
        for (int j = 0; j < EB; j++) ev[j] = es[ss[j] * 8 + hh];
#pragma unroll
        for (int j = 0; j < EB; j++) hv[j] = h[(size_t)ss[j] * 64 + lane];
#pragma unroll
        for (int j = 0; j < EB; j++) {
            float e = ev[j] + edv;
            e = (e > 0.f) ? e : 0.2f * e;
            ev[j] = (i + j < end) ? e : -1e30f;
        }
        float mx = m;
#pragma unroll
        for (int j = 0; j < EB; j++) mx = fmaxf(mx, ev[j]);
        float sc = __expf(m - mx);
        float wsum = 0.f, asum = 0.f;
#pragma unroll
        for (int j = 0; j < EB; j++) {
            float wj = __expf(ev[j] - mx);
            wsum += wj;
            asum = fmaf(wj, hv[j], asum);
        }
        acc = fmaf(acc, sc, asum);
        l = fmaf(l, sc, wsum);
        m = mx;
    }
    float o = acc / l + b[lane];
    o = (o > 0.f) ? o : expm1f(o);
    out[(size_t)node * 64 + lane] = o;
}

// ---------------- Aggregation layer 2: 1 head, fused bias + log_softmax ----------------

__global__ __launch_bounds__(256) void agg2_kernel(
    const int* __restrict__ rowptr, const int* __restrict__ col,
    const float* __restrict__ h, const float* __restrict__ es, const float* __restrict__ ed,
    const float* __restrict__ b, float* __restrict__ out, int N) {
    int node = blockIdx.x * 4 + (threadIdx.x >> 6);
    int lane = threadIdx.x & 63;
    if (node >= N) return;
    float edv = ed[node];
    float m = -1e30f, l = 0.f, acc = 0.f;
    int beg = rowptr[node], end = rowptr[node + 1];
    for (int i = beg; i < end; i += EB) {
        int ss[EB];
#pragma unroll
        for (int j = 0; j < EB; j++) {
            int idx = i + j;
            ss[j] = col[idx < end ? idx : end - 1];
        }
        float ev[EB], hv[EB];
#pragma unroll
        for (int j = 0; j < EB; j++) ev[j] = es[ss[j]];
#pragma unroll
        for (int j = 0; j < EB; j++) hv[j] = h[(size_t)ss[j] * 64 + lane];
#pragma unroll
        for (int j = 0; j < EB; j++) {
            float e = ev[j] + edv;
            e = (e > 0.f) ? e : 0.2f * e;
            ev[j] = (i + j < end) ? e : -1e30f;
        }
        float mx = m;
#pragma unroll
        for (int j = 0; j < EB; j++) mx = fmaxf(mx, ev[j]);
        float sc = __expf(m - mx);
        float wsum = 0.f, asum = 0.f;
#pragma unroll
        for (int j = 0; j < EB; j++) {
            float wj = __expf(ev[j] - mx);
            wsum += wj;
            asum = fmaf(wj, hv[j], asum);
        }
        acc = fmaf(acc, sc, asum);
        l = fmaf(l, sc, wsum);
        m = mx;
    }
    float o = acc / l + b[lane];
    // log_softmax over 64 lanes
    float M = o;
    for (int off = 32; off > 0; off >>= 1) M = fmaxf(M, __shfl_xor(M, off));
    float se = __expf(o - M);
    for (int off = 32; off > 0; off >>= 1) se += __shfl_xor(se, off);
    out[(size_t)node * 64 + lane] = o - M - logf(se);
}

// ---------------- launch ----------------

extern "C" void kernel_launch(void* const* d_in, const int* in_sizes, int n_in,
                              void* d_out, int out_size, void* d_ws, size_t ws_size,
                              hipStream_t stream) {
    const float* x   = (const float*)d_in[0];
    const int*   ei  = (const int*)d_in[1];
    const float* W1  = (const float*)d_in[2];
    const float* as1 = (const float*)d_in[3];
    const float* ad1 = (const float*)d_in[4];
    const float* b1  = (const float*)d_in[5];
    const float* W2  = (const float*)d_in[6];
    const float* as2 = (const float*)d_in[7];
    const float* ad2 = (const float*)d_in[8];
    const float* b2  = (const float*)d_in[9];
    const int N = in_sizes[0] / 300;
    const int E = in_sizes[1] / 2;
    (void)n_in; (void)out_size; (void)ws_size;

    char* w = (char*)d_ws;
    auto alloc = [&](size_t bytes) -> char* {
        char* p = w;
        w += (bytes + 255) & ~(size_t)255;
        return p;
    };
    int*   flag     = (int*)alloc(256);
    int*   deg      = (int*)alloc((size_t)(N + 1) * 4);
    int*   rowptr   = (int*)alloc((size_t)(N + 1) * 4);
    int*   cursor   = (int*)alloc((size_t)(N + 1) * 4);
    int*   partials = (int*)alloc(1024 * 4);
    int*   col      = (int*)alloc((size_t)(E + N) * 4);
    float* h1       = (float*)alloc((size_t)N * 64 * 4);
    float* h1p      = (float*)alloc((size_t)N * 64 * 4);
    float* es1      = (float*)alloc((size_t)N * 8 * 4);
    float* ed1      = (float*)alloc((size_t)N * 8 * 4);
    float* es2      = (float*)alloc((size_t)N * 4);
    float* ed2      = (float*)alloc((size_t)N * 4);
    float* h2 = h1;  // h1 dead after agg1

    hipMemsetAsync(deg, 0, (size_t)(N + 1) * sizeof(int), stream);
    detect64_kernel<<<1, 256, 0, stream>>>(ei, E, flag);

    int total = E + N;
    count_deg_kernel<<<(total + 255) / 256, 256, 0, stream>>>(ei, E, N, flag, deg);
    int M = N + 1, nb = (M + 255) / 256;  // nb must be <= 512
    scan_partial_kernel<<<nb, 256, 0, stream>>>(deg, M, partials);
    scan_partials_kernel<<<1, 512, 0, stream>>>(partials, nb);
    scan_apply_kernel<<<nb, 256, 0, stream>>>(deg, M, partials, rowptr);
    hipMemcpyAsync(cursor, rowptr, (size_t)M * 4, hipMemcpyDeviceToDevice, stream);
    fill_col_kernel<<<(total + 255) / 256, 256, 0, stream>>>(ei, E, N, flag, cursor, col);

    gemm1_kernel<<<(N + 127) / 128, 256, 0, stream>>>(x, W1, as1, ad1, h1, es1, ed1, N);
    agg1_kernel<<<(N + 3) / 4, 256, 0, stream>>>(rowptr, col, h1, es1, ed1, b1, h1p, N);
    gemm2_kernel<<<(N + 127) / 128, 256, 0, stream>>>(h1p, W2, as2, ad2, h2, es2, ed2, N);
    agg2_kernel<<<(N + 3) / 4, 256, 0, stream>>>(rowptr, col, h2, es2, ed2, b2, (float*)d_out, N);
}

// Round 3
// 607.650 us; speedup vs baseline: 1.4492x; 1.1733x over previous
//
#include <hip/hip_runtime.h>
#include <math.h>

using short8 = __attribute__((ext_vector_type(8))) short;
using f32x4  = __attribute__((ext_vector_type(4))) float;

__device__ __forceinline__ unsigned short f2bf(float f) {
    unsigned u = __float_as_uint(f);
    unsigned r = u + 0x7FFF + ((u >> 16) & 1);   // round-to-nearest-even
    return (unsigned short)(r >> 16);
}

// ---------------- CSR build ----------------

__global__ void detect64_kernel(const int* __restrict__ ei, int E, int* __restrict__ flag) {
    // If edge_index is int64, every odd int32 word (high word) is 0 (values < 2^31).
    __shared__ int any;
    if (threadIdx.x == 0) any = 0;
    __syncthreads();
    int lim = 1024;
    for (int i = threadIdx.x; i < lim; i += 256) {
        if (ei[2 * i + 1] != 0) { any = 1; break; }
    }
    __syncthreads();
    if (threadIdx.x == 0) *flag = (any ? 0 : 1);  // 1 => int64
}

__device__ __forceinline__ int edge_src(const int* ei, int E, int i, int is64) {
    return is64 ? ei[2 * i] : ei[i];
}
__device__ __forceinline__ int edge_dst(const int* ei, int E, int i, int is64) {
    return is64 ? ei[2 * (E + i)] : ei[E + i];
}

__global__ void count_deg_kernel(const int* __restrict__ ei, int E, int N,
                                 const int* __restrict__ flag, int* __restrict__ deg) {
    int i = blockIdx.x * blockDim.x + threadIdx.x;
    int total = E + N;
    if (i >= total) return;
    int is64 = *flag;
    int d = (i < E) ? edge_dst(ei, E, i, is64) : (i - E);
    atomicAdd(&deg[d], 1);
}

__global__ void scan_partial_kernel(const int* __restrict__ deg, int M, int* __restrict__ partials) {
    __shared__ int s[256];
    int t = threadIdx.x;
    int i = blockIdx.x * 256 + t;
    int v = (i < M) ? deg[i] : 0;
    s[t] = v;
    __syncthreads();
    for (int off = 128; off > 0; off >>= 1) {
        if (t < off) s[t] += s[t + off];
        __syncthreads();
    }
    if (t == 0) partials[blockIdx.x] = s[0];
}

__global__ void scan_partials_kernel(int* __restrict__ partials, int nb) {
    __shared__ int s[512];
    int t = threadIdx.x;
    int v = (t < nb) ? partials[t] : 0;
    s[t] = v;
    __syncthreads();
    for (int off = 1; off < 512; off <<= 1) {
        int x = (t >= off) ? s[t - off] : 0;
        __syncthreads();
        s[t] += x;
        __syncthreads();
    }
    if (t < nb) partials[t] = s[t] - v;  // exclusive
}

__global__ void scan_apply_kernel(const int* __restrict__ deg, int M,
                                  const int* __restrict__ partials, int* __restrict__ rowptr) {
    __shared__ int s[256];
    int t = threadIdx.x;
    int i = blockIdx.x * 256 + t;
    int v = (i < M) ? deg[i] : 0;
    s[t] = v;
    __syncthreads();
    for (int off = 1; off < 256; off <<= 1) {
        int x = (t >= off) ? s[t - off] : 0;
        __syncthreads();
        s[t] += x;
        __syncthreads();
    }
    if (i < M) rowptr[i] = s[t] - v + partials[blockIdx.x];
}

__global__ void fill_col_kernel(const int* __restrict__ ei, int E, int N,
                                const int* __restrict__ flag,
                                int* __restrict__ cursor, int* __restrict__ col) {
    int i = blockIdx.x * blockDim.x + threadIdx.x;
    int total = E + N;
    if (i >= total) return;
    int is64 = *flag;
    int s, d;
    if (i < E) { s = edge_src(ei, E, i, is64); d = edge_dst(ei, E, i, is64); }
    else       { s = i - E; d = i - E; }
    int pos = atomicAdd(&cursor[d], 1);
    col[pos] = s;
}

// ---------------- GEMM 1 (MFMA bf16): h1 = x @ W1, fused e_src/e_dst ----------------
// 128 rows x 64 cols per block, 4 waves; wave w handles rows [32w,32w+32).
// K=300 padded to 320; A,B cast to bf16 in LDS (stride 40 -> 2-way bank conflicts, free).
// C/D layout: col=lane&15, row=quad*4+reg (m89-verified).

__global__ __launch_bounds__(256) void gemm1_mfma_kernel(
    const float* __restrict__ x, const float* __restrict__ W,
    const float* __restrict__ asrc, const float* __restrict__ adst,
    float* __restrict__ h, float* __restrict__ es, float* __restrict__ ed, int N) {
    __shared__ __align__(16) unsigned short A_lds[128 * 40];
    __shared__ __align__(16) unsigned short B_lds[64 * 40];
    const int tx = threadIdx.x;
    const int wv = tx >> 6;
    const int lane = tx & 63;
    const int l15 = lane & 15;
    const int quad = lane >> 4;
    const int rowBase = blockIdx.x * 128;

    f32x4 acc[2][4];
#pragma unroll
    for (int rt = 0; rt < 2; rt++)
#pragma unroll
        for (int ct = 0; ct < 4; ct++) acc[rt][ct] = (f32x4){0.f, 0.f, 0.f, 0.f};

    const int kq = tx & 7;       // k-offset group (kq*4)
    const int r0 = tx >> 3;      // 0..31
    const int colB = tx & 63;
    const int kkb = (tx >> 6) * 8;

    for (int k0 = 0; k0 < 320; k0 += 32) {
        // stage A: 128 rows x 32 k (fp32 -> bf16)
        bool kvalid = (k0 + kq * 4 + 4 <= 300);
#pragma unroll
        for (int p = 0; p < 4; p++) {
            int row = p * 32 + r0;
            int grow = rowBase + row;
            float4 v = make_float4(0.f, 0.f, 0.f, 0.f);
            if (kvalid && grow < N) v = *(const float4*)&x[(size_t)grow * 300 + k0 + kq * 4];
            *(ushort4*)&A_lds[row * 40 + kq * 4] =
                make_ushort4(f2bf(v.x), f2bf(v.y), f2bf(v.z), f2bf(v.w));
        }
        // stage B transposed: B_lds[col][kk] = W[k0+kk][col]
        {
            unsigned short t0, t1, t2, t3, t4, t5, t6, t7;
            float v;
            v = (k0 + kkb + 0 < 300) ? W[(size_t)(k0 + kkb + 0) * 64 + colB] : 0.f; t0 = f2bf(v);
            v = (k0 + kkb + 1 < 300) ? W[(size_t)(k0 + kkb + 1) * 64 + colB] : 0.f; t1 = f2bf(v);
            v = (k0 + kkb + 2 < 300) ? W[(size_t)(k0 + kkb + 2) * 64 + colB] : 0.f; t2 = f2bf(v);
            v = (k0 + kkb + 3 < 300) ? W[(size_t)(k0 + kkb + 3) * 64 + colB] : 0.f; t3 = f2bf(v);
            v = (k0 + kkb + 4 < 300) ? W[(size_t)(k0 + kkb + 4) * 64 + colB] : 0.f; t4 = f2bf(v);
            v = (k0 + kkb + 5 < 300) ? W[(size_t)(k0 + kkb + 5) * 64 + colB] : 0.f; t5 = f2bf(v);
            v = (k0 + kkb + 6 < 300) ? W[(size_t)(k0 + kkb + 6) * 64 + colB] : 0.f; t6 = f2bf(v);
            v = (k0 + kkb + 7 < 300) ? W[(size_t)(k0 + kkb + 7) * 64 + colB] : 0.f; t7 = f2bf(v);
            *(ushort4*)&B_lds[colB * 40 + kkb]     = make_ushort4(t0, t1, t2, t3);
            *(ushort4*)&B_lds[colB * 40 + kkb + 4] = make_ushort4(t4, t5, t6, t7);
        }
        __syncthreads();
        short8 af[2], bfr[4];
#pragma unroll
        for (int rt = 0; rt < 2; rt++)
            af[rt] = *(const short8*)&A_lds[(wv * 32 + rt * 16 + l15) * 40 + quad * 8];
#pragma unroll
        for (int ct = 0; ct < 4; ct++)
            bfr[ct] = *(const short8*)&B_lds[(ct * 16 + l15) * 40 + quad * 8];
#pragma unroll
        for (int rt = 0; rt < 2; rt++)
#pragma unroll
            for (int ct = 0; ct < 4; ct++)
                acc[rt][ct] = __builtin_amdgcn_mfma_f32_16x16x32_bf16(af[rt], bfr[ct], acc[rt][ct], 0, 0, 0);
        __syncthreads();
    }

    // epilogue: store h + fused attention projections (head = col>>3; col = ct*16+l15)
    float as_v[4], ad_v[4];
#pragma unroll
    for (int ct = 0; ct < 4; ct++) {
        as_v[ct] = asrc[ct * 16 + l15];
        ad_v[ct] = adst[ct * 16 + l15];
    }
#pragma unroll
    for (int rt = 0; rt < 2; rt++) {
#pragma unroll
        for (int reg = 0; reg < 4; reg++) {
            int row = rowBase + wv * 32 + rt * 16 + quad * 4 + reg;
            bool ok = (row < N);
#pragma unroll
            for (int ct = 0; ct < 4; ct++) {
                float v = acc[rt][ct][reg];
                if (ok) h[(size_t)row * 64 + ct * 16 + l15] = v;
                float ps = v * as_v[ct];
                float pd = v * ad_v[ct];
                ps += __shfl_xor(ps, 1); ps += __shfl_xor(ps, 2); ps += __shfl_xor(ps, 4);
                pd += __shfl_xor(pd, 1); pd += __shfl_xor(pd, 2); pd += __shfl_xor(pd, 4);
                if ((lane & 7) == 0 && ok) {
                    int head = 2 * ct + ((lane >> 3) & 1);
                    es[row * 8 + head] = ps;
                    ed[row * 8 + head] = pd;
                }
            }
        }
    }
}

// ---------------- GEMM 2: h2 = h1post @ W2, fused scalar e_src/e_dst ----------------

__global__ __launch_bounds__(256) void gemm2_kernel(
    const float* __restrict__ xin, const float* __restrict__ W,
    const float* __restrict__ asrc, const float* __restrict__ adst,
    float* __restrict__ h, float* __restrict__ es, float* __restrict__ ed, int N) {
    __shared__ __align__(16) float Ws[64 * 64];
    __shared__ float xs[128 * 65];
    const int tx = threadIdx.x;
    const int cg = tx & 7;
    const int rg = tx >> 3;
    const int rowBase = blockIdx.x * 128;
    float acc[4][8];
#pragma unroll
    for (int r = 0; r < 4; r++)
#pragma unroll
        for (int c = 0; c < 8; c++) acc[r][c] = 0.f;

    for (int i = tx; i < 64 * 64; i += 256) Ws[i] = W[i];
    for (int i = tx; i < 128 * 64; i += 256) {
        int rr = i >> 6, cc = i & 63;
        int row = rowBase + rr;
        xs[rr * 65 + cc] = (row < N) ? xin[(size_t)row * 64 + cc] : 0.f;
    }
    __syncthreads();
    for (int k = 0; k < 64; k++) {
        float4 w0 = *(const float4*)&Ws[k * 64 + cg * 8];
        float4 w1 = *(const float4*)&Ws[k * 64 + cg * 8 + 4];
#pragma unroll
        for (int r = 0; r < 4; r++) {
            float xv = xs[(rg * 4 + r) * 65 + k];
            acc[r][0] = fmaf(xv, w0.x, acc[r][0]);
            acc[r][1] = fmaf(xv, w0.y, acc[r][1]);
            acc[r][2] = fmaf(xv, w0.z, acc[r][2]);
            acc[r][3] = fmaf(xv, w0.w, acc[r][3]);
            acc[r][4] = fmaf(xv, w1.x, acc[r][4]);
            acc[r][5] = fmaf(xv, w1.y, acc[r][5]);
            acc[r][6] = fmaf(xv, w1.z, acc[r][6]);
            acc[r][7] = fmaf(xv, w1.w, acc[r][7]);
        }
    }
#pragma unroll
    for (int r = 0; r < 4; r++) {
        int row = rowBase + rg * 4 + r;
        float ps = 0.f, pd = 0.f;
        if (row < N) {
            float4 o0 = make_float4(acc[r][0], acc[r][1], acc[r][2], acc[r][3]);
            float4 o1 = make_float4(acc[r][4], acc[r][5], acc[r][6], acc[r][7]);
            *(float4*)&h[(size_t)row * 64 + cg * 8] = o0;
            *(float4*)&h[(size_t)row * 64 + cg * 8 + 4] = o1;
#pragma unroll
            for (int c = 0; c < 8; c++) {
                ps = fmaf(acc[r][c], asrc[cg * 8 + c], ps);
                pd = fmaf(acc[r][c], adst[cg * 8 + c], pd);
            }
        }
        for (int off = 1; off < 8; off <<= 1) {
            ps += __shfl_xor(ps, off);
            pd += __shfl_xor(pd, off);
        }
        if (cg == 0 && row < N) { es[row] = ps; ed[row] = pd; }
    }
}

// ---------------- Aggregation layer 1: online edge-softmax, 8 heads, fused bias+ELU ----------------

#define EB 8
__global__ __launch_bounds__(256) void agg1_kernel(
    const int* __restrict__ rowptr, const int* __restrict__ col,
    const float* __restrict__ h, const float* __restrict__ es, const float* __restrict__ ed,
    const float* __restrict__ b, float* __restrict__ out, int N) {
    int node = blockIdx.x * 4 + (threadIdx.x >> 6);
    int lane = threadIdx.x & 63;
    if (node >= N) return;
    int hh = lane >> 3;
    float edv = ed[node * 8 + hh];
    float m = -1e30f, l = 0.f, acc = 0.f;
    int beg = rowptr[node], end = rowptr[node + 1];
    for (int i = beg; i < end; i += EB) {
        int ss[EB];
#pragma unroll
        for (int j = 0; j < EB; j++) {
            int idx = i + j;
            ss[j] = col[idx < end ? idx : end - 1];
        }
        float ev[EB], hv[EB];
#pragma unroll
        for (int j = 0; j < EB; j++) ev[j] = es[ss[j] * 8 + hh];
#pragma unroll
        for (int j = 0; j < EB; j++) hv[j] = h[(size_t)ss[j] * 64 + lane];
#pragma unroll
        for (int j = 0; j < EB; j++) {
            float e = ev[j] + edv;
            e = (e > 0.f) ? e : 0.2f * e;
            ev[j] = (i + j < end) ? e : -1e30f;
        }
        float mx = m;
#pragma unroll
        for (int j = 0; j < EB; j++) mx = fmaxf(mx, ev[j]);
        float sc = __expf(m - mx);
        float wsum = 0.f, asum = 0.f;
#pragma unroll
        for (int j = 0; j < EB; j++) {
            float wj = __expf(ev[j] - mx);
            wsum += wj;
            asum = fmaf(wj, hv[j], asum);
        }
        acc = fmaf(acc, sc, asum);
        l = fmaf(l, sc, wsum);
        m = mx;
    }
    float o = acc / l + b[lane];
    o = (o > 0.f) ? o : expm1f(o);
    out[(size_t)node * 64 + lane] = o;
}

// ---------------- Aggregation layer 2: 1 head, fused bias + log_softmax ----------------

__global__ __launch_bounds__(256) void agg2_kernel(
    const int* __restrict__ rowptr, const int* __restrict__ col,
    const float* __restrict__ h, const float* __restrict__ es, const float* __restrict__ ed,
    const float* __restrict__ b, float* __restrict__ out, int N) {
    int node = blockIdx.x * 4 + (threadIdx.x >> 6);
    int lane = threadIdx.x & 63;
    if (node >= N) return;
    float edv = ed[node];
    float m = -1e30f, l = 0.f, acc = 0.f;
    int beg = rowptr[node], end = rowptr[node + 1];
    for (int i = beg; i < end; i += EB) {
        int ss[EB];
#pragma unroll
        for (int j = 0; j < EB; j++) {
            int idx = i + j;
            ss[j] = col[idx < end ? idx : end - 1];
        }
        float ev[EB], hv[EB];
#pragma unroll
        for (int j = 0; j < EB; j++) ev[j] = es[ss[j]];
#pragma unroll
        for (int j = 0; j < EB; j++) hv[j] = h[(size_t)ss[j] * 64 + lane];
#pragma unroll
        for (int j = 0; j < EB; j++) {
            float e = ev[j] + edv;
            e = (e > 0.f) ? e : 0.2f * e;
            ev[j] = (i + j < end) ? e : -1e30f;
        }
        float mx = m;
#pragma unroll
        for (int j = 0; j < EB; j++) mx = fmaxf(mx, ev[j]);
        float sc = __expf(m - mx);
        float wsum = 0.f, asum = 0.f;
#pragma unroll
        for (int j = 0; j < EB; j++) {
            float wj = __expf(ev[j] - mx);
            wsum += wj;
            asum = fmaf(wj, hv[j], asum);
        }
        acc = fmaf(acc, sc, asum);
        l = fmaf(l, sc, wsum);
        m = mx;
    }
    float o = acc / l + b[lane];
    float M = o;
    for (int off = 32; off > 0; off >>= 1) M = fmaxf(M, __shfl_xor(M, off));
    float se = __expf(o - M);
    for (int off = 32; off > 0; off >>= 1) se += __shfl_xor(se, off);
    out[(size_t)node * 64 + lane] = o - M - logf(se);
}

// ---------------- launch ----------------

extern "C" void kernel_launch(void* const* d_in, const int* in_sizes, int n_in,
                              void* d_out, int out_size, void* d_ws, size_t ws_size,
                              hipStream_t stream) {
    const float* x   = (const float*)d_in[0];
    const int*   ei  = (const int*)d_in[1];
    const float* W1  = (const float*)d_in[2];
    const float* as1 = (const float*)d_in[3];
    const float* ad1 = (const float*)d_in[4];
    const float* b1  = (const float*)d_in[5];
    const float* W2  = (const float*)d_in[6];
    const float* as2 = (const float*)d_in[7];
    const float* ad2 = (const float*)d_in[8];
    const float* b2  = (const float*)d_in[9];
    const int N = in_sizes[0] / 300;
    const int E = in_sizes[1] / 2;
    (void)n_in; (void)out_size; (void)ws_size;

    char* w = (char*)d_ws;
    auto alloc = [&](size_t bytes) -> char* {
        char* p = w;
        w += (bytes + 255) & ~(size_t)255;
        return p;
    };
    int*   flag     = (int*)alloc(256);
    int*   deg      = (int*)alloc((size_t)(N + 1) * 4);
    int*   rowptr   = (int*)alloc((size_t)(N + 1) * 4);
    int*   cursor   = (int*)alloc((size_t)(N + 1) * 4);
    int*   partials = (int*)alloc(1024 * 4);
    int*   col      = (int*)alloc((size_t)(E + N) * 4);
    float* h1       = (float*)alloc((size_t)N * 64 * 4);
    float* h1p      = (float*)alloc((size_t)N * 64 * 4);
    float* es1      = (float*)alloc((size_t)N * 8 * 4);
    float* ed1      = (float*)alloc((size_t)N * 8 * 4);
    float* es2      = (float*)alloc((size_t)N * 4);
    float* ed2      = (float*)alloc((size_t)N * 4);
    float* h2 = h1;  // h1 dead after agg1

    hipMemsetAsync(deg, 0, (size_t)(N + 1) * sizeof(int), stream);
    detect64_kernel<<<1, 256, 0, stream>>>(ei, E, flag);

    int total = E + N;
    count_deg_kernel<<<(total + 255) / 256, 256, 0, stream>>>(ei, E, N, flag, deg);
    int M = N + 1, nb = (M + 255) / 256;  // nb must be <= 512
    scan_partial_kernel<<<nb, 256, 0, stream>>>(deg, M, partials);
    scan_partials_kernel<<<1, 512, 0, stream>>>(partials, nb);
    scan_apply_kernel<<<nb, 256, 0, stream>>>(deg, M, partials, rowptr);
    hipMemcpyAsync(cursor, rowptr, (size_t)M * 4, hipMemcpyDeviceToDevice, stream);
    fill_col_kernel<<<(total + 255) / 256, 256, 0, stream>>>(ei, E, N, flag, cursor, col);

    gemm1_mfma_kernel<<<(N + 127) / 128, 256, 0, stream>>>(x, W1, as1, ad1, h1, es1, ed1, N);
    agg1_kernel<<<(N + 3) / 4, 256, 0, stream>>>(rowptr, col, h1, es1, ed1, b1, h1p, N);
    gemm2_kernel<<<(N + 127) / 128, 256, 0, stream>>>(h1p, W2, as2, ad2, h2, es2, ed2, N);
    agg2_kernel<<<(N + 3) / 4, 256, 0, stream>>>(rowptr, col, h2, es2, ed2, b2, (float*)d_out, N);
}

// Round 4
// 510.960 us; speedup vs baseline: 1.7235x; 1.1892x over previous
//
#include <hip/hip_runtime.h>
#include <math.h>

using short8 = __attribute__((ext_vector_type(8))) short;
using f32x4  = __attribute__((ext_vector_type(4))) float;

#define NBLKS 512
#define BPAD  800   // padded bucket count (nbuck <= 800)

__device__ __forceinline__ unsigned short f2bf(float f) {
    unsigned u = __float_as_uint(f);
    unsigned r = u + 0x7FFF + ((u >> 16) & 1);   // round-to-nearest-even
    return (unsigned short)(r >> 16);
}

// ---------------- edge dtype detect ----------------

__global__ void detect64_kernel(const int* __restrict__ ei, int E, int* __restrict__ flag) {
    __shared__ int any;
    if (threadIdx.x == 0) any = 0;
    __syncthreads();
    for (int i = threadIdx.x; i < 1024; i += 256) {
        if (ei[2 * i + 1] != 0) { any = 1; break; }
    }
    __syncthreads();
    if (threadIdx.x == 0) *flag = (any ? 0 : 1);  // 1 => int64
}

// ---------------- CSR build: two-level counting sort, zero global atomics ----------------
// Bucket = dst>>7 (128 nodes/bucket). Pass A: per-block coarse histograms (LDS).
// Scan along blocks per bucket + cross-bucket scan -> reserved ranges.
// Pass B: scatter packed (dstLocal<<17|src) into bucket-ordered tmp.
// Pass C: per-bucket exact counting sort -> rowptr + col.

__global__ __launch_bounds__(256) void binA_kernel(
    const int* __restrict__ ei, int E, int N, const int* __restrict__ flag,
    int nbuck, int* __restrict__ hist, int chunk) {
    __shared__ int lh[BPAD];
    for (int i = threadIdx.x; i < nbuck; i += 256) lh[i] = 0;
    __syncthreads();
    int is64 = *flag;
    int Etot = E + N;
    int beg = blockIdx.x * chunk, end = min(Etot, beg + chunk);
    for (int i = beg + threadIdx.x; i < end; i += 256) {
        int d = (i < E) ? (is64 ? ei[2 * (E + i)] : ei[E + i]) : (i - E);
        atomicAdd(&lh[d >> 7], 1);
    }
    __syncthreads();
    for (int i = threadIdx.x; i < nbuck; i += 256) hist[blockIdx.x * BPAD + i] = lh[i];
}

__global__ void scanBlocks_kernel(int* __restrict__ hist, int nbuck, int* __restrict__ bucketTotal) {
    int bin = blockIdx.x * 256 + threadIdx.x;
    if (bin >= nbuck) return;
    int run = 0;
    for (int b = 0; b < NBLKS; b++) {
        int v = hist[b * BPAD + bin];
        hist[b * BPAD + bin] = run;
        run += v;
    }
    bucketTotal[bin] = run;
}

__global__ void scanBucket_kernel(const int* __restrict__ bucketTotal, int nbuck,
                                  int* __restrict__ bucketBase) {
    __shared__ int s[1024];
    int t = threadIdx.x;
    int v = (t < nbuck) ? bucketTotal[t] : 0;
    s[t] = v;
    __syncthreads();
    for (int off = 1; off < 1024; off <<= 1) {
        int x = (t >= off) ? s[t - off] : 0;
        __syncthreads();
        s[t] += x;
        __syncthreads();
    }
    if (t < nbuck) bucketBase[t] = s[t] - v;
    if (t == nbuck - 1) bucketBase[nbuck] = s[t];
}

__global__ __launch_bounds__(256) void binB_kernel(
    const int* __restrict__ ei, int E, int N, const int* __restrict__ flag,
    int nbuck, const int* __restrict__ hist, const int* __restrict__ bucketBase,
    int* __restrict__ tmp, int chunk) {
    __shared__ int cur[BPAD];
    for (int i = threadIdx.x; i < nbuck; i += 256)
        cur[i] = bucketBase[i] + hist[blockIdx.x * BPAD + i];
    __syncthreads();
    int is64 = *flag;
    int Etot = E + N;
    int beg = blockIdx.x * chunk, end = min(Etot, beg + chunk);
    for (int i = beg + threadIdx.x; i < end; i += 256) {
        int s, d;
        if (i < E) {
            if (is64) { s = ei[2 * i]; d = ei[2 * (E + i)]; }
            else      { s = ei[i];     d = ei[E + i]; }
        } else { s = i - E; d = i - E; }
        int pos = atomicAdd(&cur[d >> 7], 1);
        tmp[pos] = ((d & 127) << 17) | s;   // src < 2^17
    }
}

__global__ __launch_bounds__(256) void binC_kernel(
    const int* __restrict__ tmp, const int* __restrict__ bucketBase, int nbuck,
    int N, int Etot, int* __restrict__ rowptr, int* __restrict__ col) {
    __shared__ int lh[128];
    __shared__ int cur[128];
    int g = blockIdx.x;
    int t = threadIdx.x;
    int beg = bucketBase[g], end = bucketBase[g + 1];
    if (t < 128) lh[t] = 0;
    __syncthreads();
    for (int i = beg + t; i < end; i += 256) atomicAdd(&lh[tmp[i] >> 17], 1);
    __syncthreads();
    int c = (t < 128) ? lh[t] : 0;
    // inclusive scan over 128 bins
    for (int off = 1; off < 128; off <<= 1) {
        int x = 0;
        if (t < 128 && t >= off) x = lh[t - off];
        __syncthreads();
        if (t < 128) lh[t] += x;
        __syncthreads();
    }
    if (t < 128) {
        int excl = lh[t] - c;
        cur[t] = beg + excl;
        int node = g * 128 + t;
        if (node < N) rowptr[node] = beg + excl;
    }
    if (g == 0 && t == 0) rowptr[N] = Etot;
    __syncthreads();
    for (int i = beg + t; i < end; i += 256) {
        int v = tmp[i];
        int pos = atomicAdd(&cur[v >> 17], 1);
        col[pos] = v & 0x1FFFF;
    }
}

// ---------------- GEMM 1 (MFMA bf16): h1 = x @ W1, fused e_src/e_dst ----------------

__global__ __launch_bounds__(256) void gemm1_mfma_kernel(
    const float* __restrict__ x, const float* __restrict__ W,
    const float* __restrict__ asrc, const float* __restrict__ adst,
    float* __restrict__ h, float* __restrict__ es, float* __restrict__ ed, int N) {
    __shared__ __align__(16) unsigned short A_lds[128 * 40];
    __shared__ __align__(16) unsigned short B_lds[64 * 40];
    const int tx = threadIdx.x;
    const int wv = tx >> 6;
    const int lane = tx & 63;
    const int l15 = lane & 15;
    const int quad = lane >> 4;
    const int rowBase = blockIdx.x * 128;

    f32x4 acc[2][4];
#pragma unroll
    for (int rt = 0; rt < 2; rt++)
#pragma unroll
        for (int ct = 0; ct < 4; ct++) acc[rt][ct] = (f32x4){0.f, 0.f, 0.f, 0.f};

    const int kq = tx & 7;
    const int r0 = tx >> 3;
    const int colB = tx & 63;
    const int kkb = (tx >> 6) * 8;

    for (int k0 = 0; k0 < 320; k0 += 32) {
        bool kvalid = (k0 + kq * 4 + 4 <= 300);
#pragma unroll
        for (int p = 0; p < 4; p++) {
            int row = p * 32 + r0;
            int grow = rowBase + row;
            float4 v = make_float4(0.f, 0.f, 0.f, 0.f);
            if (kvalid && grow < N) v = *(const float4*)&x[(size_t)grow * 300 + k0 + kq * 4];
            *(ushort4*)&A_lds[row * 40 + kq * 4] =
                make_ushort4(f2bf(v.x), f2bf(v.y), f2bf(v.z), f2bf(v.w));
        }
        {
            unsigned short t0, t1, t2, t3, t4, t5, t6, t7;
            float v;
            v = (k0 + kkb + 0 < 300) ? W[(size_t)(k0 + kkb + 0) * 64 + colB] : 0.f; t0 = f2bf(v);
            v = (k0 + kkb + 1 < 300) ? W[(size_t)(k0 + kkb + 1) * 64 + colB] : 0.f; t1 = f2bf(v);
            v = (k0 + kkb + 2 < 300) ? W[(size_t)(k0 + kkb + 2) * 64 + colB] : 0.f; t2 = f2bf(v);
            v = (k0 + kkb + 3 < 300) ? W[(size_t)(k0 + kkb + 3) * 64 + colB] : 0.f; t3 = f2bf(v);
            v = (k0 + kkb + 4 < 300) ? W[(size_t)(k0 + kkb + 4) * 64 + colB] : 0.f; t4 = f2bf(v);
            v = (k0 + kkb + 5 < 300) ? W[(size_t)(k0 + kkb + 5) * 64 + colB] : 0.f; t5 = f2bf(v);
            v = (k0 + kkb + 6 < 300) ? W[(size_t)(k0 + kkb + 6) * 64 + colB] : 0.f; t6 = f2bf(v);
            v = (k0 + kkb + 7 < 300) ? W[(size_t)(k0 + kkb + 7) * 64 + colB] : 0.f; t7 = f2bf(v);
            *(ushort4*)&B_lds[colB * 40 + kkb]     = make_ushort4(t0, t1, t2, t3);
            *(ushort4*)&B_lds[colB * 40 + kkb + 4] = make_ushort4(t4, t5, t6, t7);
        }
        __syncthreads();
        short8 af[2], bfr[4];
#pragma unroll
        for (int rt = 0; rt < 2; rt++)
            af[rt] = *(const short8*)&A_lds[(wv * 32 + rt * 16 + l15) * 40 + quad * 8];
#pragma unroll
        for (int ct = 0; ct < 4; ct++)
            bfr[ct] = *(const short8*)&B_lds[(ct * 16 + l15) * 40 + quad * 8];
#pragma unroll
        for (int rt = 0; rt < 2; rt++)
#pragma unroll
            for (int ct = 0; ct < 4; ct++)
                acc[rt][ct] = __builtin_amdgcn_mfma_f32_16x16x32_bf16(af[rt], bfr[ct], acc[rt][ct], 0, 0, 0);
        __syncthreads();
    }

    float as_v[4], ad_v[4];
#pragma unroll
    for (int ct = 0; ct < 4; ct++) {
        as_v[ct] = asrc[ct * 16 + l15];
        ad_v[ct] = adst[ct * 16 + l15];
    }
#pragma unroll
    for (int rt = 0; rt < 2; rt++) {
#pragma unroll
        for (int reg = 0; reg < 4; reg++) {
            int row = rowBase + wv * 32 + rt * 16 + quad * 4 + reg;
            bool ok = (row < N);
#pragma unroll
            for (int ct = 0; ct < 4; ct++) {
                float v = acc[rt][ct][reg];
                if (ok) h[(size_t)row * 64 + ct * 16 + l15] = v;
                float ps = v * as_v[ct];
                float pd = v * ad_v[ct];
                ps += __shfl_xor(ps, 1); ps += __shfl_xor(ps, 2); ps += __shfl_xor(ps, 4);
                pd += __shfl_xor(pd, 1); pd += __shfl_xor(pd, 2); pd += __shfl_xor(pd, 4);
                if ((lane & 7) == 0 && ok) {
                    int head = 2 * ct + ((lane >> 3) & 1);
                    es[row * 8 + head] = ps;
                    ed[row * 8 + head] = pd;
                }
            }
        }
    }
}

// ---------------- GEMM 2: h2 = h1post @ W2, fused scalar e_src/e_dst ----------------

__global__ __launch_bounds__(256) void gemm2_kernel(
    const float* __restrict__ xin, const float* __restrict__ W,
    const float* __restrict__ asrc, const float* __restrict__ adst,
    float* __restrict__ h, float* __restrict__ es, float* __restrict__ ed, int N) {
    __shared__ __align__(16) float Ws[64 * 64];
    __shared__ float xs[128 * 65];
    const int tx = threadIdx.x;
    const int cg = tx & 7;
    const int rg = tx >> 3;
    const int rowBase = blockIdx.x * 128;
    float acc[4][8];
#pragma unroll
    for (int r = 0; r < 4; r++)
#pragma unroll
        for (int c = 0; c < 8; c++) acc[r][c] = 0.f;

    for (int i = tx; i < 64 * 64; i += 256) Ws[i] = W[i];
    for (int i = tx; i < 128 * 64; i += 256) {
        int rr = i >> 6, cc = i & 63;
        int row = rowBase + rr;
        xs[rr * 65 + cc] = (row < N) ? xin[(size_t)row * 64 + cc] : 0.f;
    }
    __syncthreads();
    for (int k = 0; k < 64; k++) {
        float4 w0 = *(const float4*)&Ws[k * 64 + cg * 8];
        float4 w1 = *(const float4*)&Ws[k * 64 + cg * 8 + 4];
#pragma unroll
        for (int r = 0; r < 4; r++) {
            float xv = xs[(rg * 4 + r) * 65 + k];
            acc[r][0] = fmaf(xv, w0.x, acc[r][0]);
            acc[r][1] = fmaf(xv, w0.y, acc[r][1]);
            acc[r][2] = fmaf(xv, w0.z, acc[r][2]);
            acc[r][3] = fmaf(xv, w0.w, acc[r][3]);
            acc[r][4] = fmaf(xv, w1.x, acc[r][4]);
            acc[r][5] = fmaf(xv, w1.y, acc[r][5]);
            acc[r][6] = fmaf(xv, w1.z, acc[r][6]);
            acc[r][7] = fmaf(xv, w1.w, acc[r][7]);
        }
    }
#pragma unroll
    for (int r = 0; r < 4; r++) {
        int row = rowBase + rg * 4 + r;
        float ps = 0.f, pd = 0.f;
        if (row < N) {
            float4 o0 = make_float4(acc[r][0], acc[r][1], acc[r][2], acc[r][3]);
            float4 o1 = make_float4(acc[r][4], acc[r][5], acc[r][6], acc[r][7]);
            *(float4*)&h[(size_t)row * 64 + cg * 8] = o0;
            *(float4*)&h[(size_t)row * 64 + cg * 8 + 4] = o1;
#pragma unroll
            for (int c = 0; c < 8; c++) {
                ps = fmaf(acc[r][c], asrc[cg * 8 + c], ps);
                pd = fmaf(acc[r][c], adst[cg * 8 + c], pd);
            }
        }
        for (int off = 1; off < 8; off <<= 1) {
            ps += __shfl_xor(ps, off);
            pd += __shfl_xor(pd, off);
        }
        if (cg == 0 && row < N) { es[row] = ps; ed[row] = pd; }
    }
}

// ---------------- Aggregation layer 1 ----------------

#define EB 8
__global__ __launch_bounds__(256) void agg1_kernel(
    const int* __restrict__ rowptr, const int* __restrict__ col,
    const float* __restrict__ h, const float* __restrict__ es, const float* __restrict__ ed,
    const float* __restrict__ b, float* __restrict__ out, int N) {
    int node = blockIdx.x * 4 + (threadIdx.x >> 6);
    int lane = threadIdx.x & 63;
    if (node >= N) return;
    int hh = lane >> 3;
    float edv = ed[node * 8 + hh];
    float m = -1e30f, l = 0.f, acc = 0.f;
    int beg = rowptr[node], end = rowptr[node + 1];
    for (int i = beg; i < end; i += EB) {
        int ss[EB];
#pragma unroll
        for (int j = 0; j < EB; j++) {
            int idx = i + j;
            ss[j] = col[idx < end ? idx : end - 1];
        }
        float ev[EB], hv[EB];
#pragma unroll
        for (int j = 0; j < EB; j++) ev[j] = es[ss[j] * 8 + hh];
#pragma unroll
        for (int j = 0; j < EB; j++) hv[j] = h[(size_t)ss[j] * 64 + lane];
#pragma unroll
        for (int j = 0; j < EB; j++) {
            float e = ev[j] + edv;
            e = (e > 0.f) ? e : 0.2f * e;
            ev[j] = (i + j < end) ? e : -1e30f;
        }
        float mx = m;
#pragma unroll
        for (int j = 0; j < EB; j++) mx = fmaxf(mx, ev[j]);
        float sc = __expf(m - mx);
        float wsum = 0.f, asum = 0.f;
#pragma unroll
        for (int j = 0; j < EB; j++) {
            float wj = __expf(ev[j] - mx);
            wsum += wj;
            asum = fmaf(wj, hv[j], asum);
        }
        acc = fmaf(acc, sc, asum);
        l = fmaf(l, sc, wsum);
        m = mx;
    }
    float o = acc / l + b[lane];
    o = (o > 0.f) ? o : expm1f(o);
    out[(size_t)node * 64 + lane] = o;
}

// ---------------- Aggregation layer 2 ----------------

__global__ __launch_bounds__(256) void agg2_kernel(
    const int* __restrict__ rowptr, const int* __restrict__ col,
    const float* __restrict__ h, const float* __restrict__ es, const float* __restrict__ ed,
    const float* __restrict__ b, float* __restrict__ out, int N) {
    int node = blockIdx.x * 4 + (threadIdx.x >> 6);
    int lane = threadIdx.x & 63;
    if (node >= N) return;
    float edv = ed[node];
    float m = -1e30f, l = 0.f, acc = 0.f;
    int beg = rowptr[node], end = rowptr[node + 1];
    for (int i = beg; i < end; i += EB) {
        int ss[EB];
#pragma unroll
        for (int j = 0; j < EB; j++) {
            int idx = i + j;
            ss[j] = col[idx < end ? idx : end - 1];
        }
        float ev[EB], hv[EB];
#pragma unroll
        for (int j = 0; j < EB; j++) ev[j] = es[ss[j]];
#pragma unroll
        for (int j = 0; j < EB; j++) hv[j] = h[(size_t)ss[j] * 64 + lane];
#pragma unroll
        for (int j = 0; j < EB; j++) {
            float e = ev[j] + edv;
            e = (e > 0.f) ? e : 0.2f * e;
            ev[j] = (i + j < end) ? e : -1e30f;
        }
        float mx = m;
#pragma unroll
        for (int j = 0; j < EB; j++) mx = fmaxf(mx, ev[j]);
        float sc = __expf(m - mx);
        float wsum = 0.f, asum = 0.f;
#pragma unroll
        for (int j = 0; j < EB; j++) {
            float wj = __expf(ev[j] - mx);
            wsum += wj;
            asum = fmaf(wj, hv[j], asum);
        }
        acc = fmaf(acc, sc, asum);
        l = fmaf(l, sc, wsum);
        m = mx;
    }
    float o = acc / l + b[lane];
    float M = o;
    for (int off = 32; off > 0; off >>= 1) M = fmaxf(M, __shfl_xor(M, off));
    float se = __expf(o - M);
    for (int off = 32; off > 0; off >>= 1) se += __shfl_xor(se, off);
    out[(size_t)node * 64 + lane] = o - M - logf(se);
}

// ---------------- launch ----------------

extern "C" void kernel_launch(void* const* d_in, const int* in_sizes, int n_in,
                              void* d_out, int out_size, void* d_ws, size_t ws_size,
                              hipStream_t stream) {
    const float* x   = (const float*)d_in[0];
    const int*   ei  = (const int*)d_in[1];
    const float* W1  = (const float*)d_in[2];
    const float* as1 = (const float*)d_in[3];
    const float* ad1 = (const float*)d_in[4];
    const float* b1  = (const float*)d_in[5];
    const float* W2  = (const float*)d_in[6];
    const float* as2 = (const float*)d_in[7];
    const float* ad2 = (const float*)d_in[8];
    const float* b2  = (const float*)d_in[9];
    const int N = in_sizes[0] / 300;
    const int E = in_sizes[1] / 2;
    const int Etot = E + N;
    const int nbuck = (N + 127) >> 7;   // <= 800
    (void)n_in; (void)out_size; (void)ws_size;

    char* w = (char*)d_ws;
    auto alloc = [&](size_t bytes) -> char* {
        char* p = w;
        w += (bytes + 255) & ~(size_t)255;
        return p;
    };
    int*   flag        = (int*)alloc(256);
    int*   hist        = (int*)alloc((size_t)NBLKS * BPAD * 4);
    int*   bucketTotal = (int*)alloc((size_t)(BPAD + 1) * 4);
    int*   bucketBase  = (int*)alloc((size_t)(BPAD + 1) * 4);
    int*   tmp         = (int*)alloc((size_t)Etot * 4);
    int*   rowptr      = (int*)alloc((size_t)(N + 1) * 4);
    int*   col         = (int*)alloc((size_t)Etot * 4);
    float* h1          = (float*)alloc((size_t)N * 64 * 4);
    float* h1p         = (float*)alloc((size_t)N * 64 * 4);
    float* es1         = (float*)alloc((size_t)N * 8 * 4);
    float* ed1         = (float*)alloc((size_t)N * 8 * 4);
    float* es2         = (float*)alloc((size_t)N * 4);
    float* ed2         = (float*)alloc((size_t)N * 4);
    float* h2 = h1;  // h1 dead after agg1

    detect64_kernel<<<1, 256, 0, stream>>>(ei, E, flag);

    int chunk = (Etot + NBLKS - 1) / NBLKS;
    binA_kernel<<<NBLKS, 256, 0, stream>>>(ei, E, N, flag, nbuck, hist, chunk);
    scanBlocks_kernel<<<(nbuck + 255) / 256, 256, 0, stream>>>(hist, nbuck, bucketTotal);
    scanBucket_kernel<<<1, 1024, 0, stream>>>(bucketTotal, nbuck, bucketBase);
    binB_kernel<<<NBLKS, 256, 0, stream>>>(ei, E, N, flag, nbuck, hist, bucketBase, tmp, chunk);
    binC_kernel<<<nbuck, 256, 0, stream>>>(tmp, bucketBase, nbuck, N, Etot, rowptr, col);

    gemm1_mfma_kernel<<<(N + 127) / 128, 256, 0, stream>>>(x, W1, as1, ad1, h1, es1, ed1, N);
    agg1_kernel<<<(N + 3) / 4, 256, 0, stream>>>(rowptr, col, h1, es1, ed1, b1, h1p, N);
    gemm2_kernel<<<(N + 127) / 128, 256, 0, stream>>>(h1p, W2, as2, ad2, h2, es2, ed2, N);
    agg2_kernel<<<(N + 3) / 4, 256, 0, stream>>>(rowptr, col, h2, es2, ed2, b2, (float*)d_out, N);
}